// Round 5
// baseline (3529.892 us; speedup 1.0000x reference)
//
#include <hip/hip_runtime.h>
#include <hip/hip_bf16.h>
#include <math.h>

typedef __attribute__((ext_vector_type(8))) short bf16x8;
typedef __attribute__((ext_vector_type(4))) float f32x4;

constexpr int NPTS = 65536;
constexpr int ENC  = 512;
constexpr int P    = 4096;
constexpr int JD   = 1024;   // 2*ENC
constexpr int ID   = 8192;   // 2*P
constexpr int CH   = 8192;   // point chunk
constexpr int NCH  = NPTS / CH;
constexpr int LDK  = 8192;   // k-stride (elements) of all GEMM operand rows

constexpr float INV_R   = 20.0f;                  // 1/0.05
constexpr float INV2PI  = 0.15915494309189535f;
constexpr float SQRT_D  = 22.627416997969522f;    // sqrt(512)

__device__ __forceinline__ unsigned short f2bf(float f) {
    unsigned int u = __float_as_uint(f);
    u = (u + 0x7FFFu + ((u >> 16) & 1u)) >> 16;
    return (unsigned short)u;
}

// phases are up to ~±350 revolutions: must fract-reduce before v_sin/v_cos
__device__ __forceinline__ void sincos_rev(float p, float* s, float* c) {
    float r = p * INV2PI;
    r = r - floorf(r);                 // [0,1)
    *s = __builtin_amdgcn_sinf(r);     // sin(2*pi*r)
    *c = __builtin_amdgcn_cosf(r);
}

__device__ __forceinline__ void gload16(const void* g, void* l) {
    __builtin_amdgcn_global_load_lds(
        (const __attribute__((address_space(1))) unsigned int*)g,
        (__attribute__((address_space(3))) unsigned int*)l, 16, 0, 0);
}

// ---------------- gen transposed e-matrices (phase A) ----------------
__global__ __launch_bounds__(256)
void gen_t(const float* __restrict__ pts, const float* __restrict__ A,
           const float* __restrict__ B, unsigned short* __restrict__ eAT,
           unsigned short* __restrict__ eBT, int n0) {
    int idx = blockIdx.x * 256 + threadIdx.x;
    int nh  = idx & (CH / 2 - 1);      // 4096 pairs
    int r   = idx >> 12;               // row in [0, 4608): first 512 = A rows
    int nl  = nh * 2;
    int n   = n0 + nl;
    float x0a = pts[n * 3 + 0], x1a = pts[n * 3 + 1], x2a = pts[n * 3 + 2];
    float x0b = pts[n * 3 + 3], x1b = pts[n * 3 + 4], x2b = pts[n * 3 + 5];
    float w0, w1, w2;
    unsigned short *dc, *dsn;
    if (r < ENC) {
        w0 = A[r]; w1 = A[ENC + r]; w2 = A[2 * ENC + r];
        dc  = eAT + (size_t)r * CH + nl;
        dsn = eAT + (size_t)(r + ENC) * CH + nl;
    } else {
        int i = r - ENC;
        w0 = B[i]; w1 = B[P + i]; w2 = B[2 * P + i];
        dc  = eBT + (size_t)i * CH + nl;
        dsn = eBT + (size_t)(i + P) * CH + nl;
    }
    float pa = (x0a * w0 + x1a * w1 + x2a * w2) * INV_R;
    float pb = (x0b * w0 + x1b * w1 + x2b * w2) * INV_R;
    float sa, ca, sb, cb;
    sincos_rev(pa, &sa, &ca);
    sincos_rev(pb, &sb, &cb);
    ushort2 vc; vc.x = f2bf(ca); vc.y = f2bf(cb);
    ushort2 vs; vs.x = f2bf(sa); vs.y = f2bf(sb);
    *(ushort2*)dc  = vc;
    *(ushort2*)dsn = vs;
}

// ---------------- gen eB row-major (phase C) ----------------
__global__ __launch_bounds__(256)
void gen_b(const float* __restrict__ pts, const float* __restrict__ B,
           unsigned short* __restrict__ eB, int n0) {
    int idx = blockIdx.x * 256 + threadIdx.x;
    int ih = idx & 2047;
    int ln = idx >> 11;
    int i  = ih * 2;
    int n  = n0 + ln;
    float x0 = pts[n * 3 + 0], x1 = pts[n * 3 + 1], x2 = pts[n * 3 + 2];
    float p0 = (x0 * B[i]     + x1 * B[P + i]     + x2 * B[2 * P + i])     * INV_R;
    float p1 = (x0 * B[i + 1] + x1 * B[P + i + 1] + x2 * B[2 * P + i + 1]) * INV_R;
    float s0, c0, s1, c1;
    sincos_rev(p0, &s0, &c0);
    sincos_rev(p1, &s1, &c1);
    ushort2 vc; vc.x = f2bf(c0); vc.y = f2bf(c1);
    ushort2 vs; vs.x = f2bf(s0); vs.y = f2bf(s1);
    *(ushort2*)(eB + (size_t)ln * ID + i)     = vc;
    *(ushort2*)(eB + (size_t)ln * ID + P + i) = vs;
}

// ---------------- 8-phase GEMM (m201 port): C[m][n] += sum_k A[m][k]B[n][k]
// 256x256 tile, split-K=2 (grid.z), 512 thr = 8 waves (2M x 4N), wave tile
// 128x64 (43.7 FLOP/LDS-byte), BK=64, double-buffered 128 KiB LDS.
// Per K-tile: 4 phases, each {ds_read subtile || stage 1 half-tile ->
// barrier -> lgkmcnt(0)+sched_barrier(0) -> setprio(1) 16 MFMA setprio(0)
// -> barrier}. Quadrant order Q00,Q01,Q11,Q10: every phase's reads are
// consumed by that phase's MFMAs, so the lgkm(0) drain guarantees a
// region's reads completed before its re-staging 2+ barriers later.
// Region retirement: A-halves of kt+1 staged P1/P2 (into other buffer,
// idle since kt-1); B region of THIS buffer retires at P2-end -> B-halves
// of kt+2 staged P3/P4. Counted vmcnt(4) once per K-tile at P4 (the 4
// youngest loads = B(kt+2)); never 0 mid-loop.
// Split-K + chunk accumulation via atomicAdd onto pre-zeroed C
// (commutative fp32 adds; reorder noise << tolerance).
__global__ __launch_bounds__(512, 2)
void gemm8p(const unsigned short* __restrict__ Ag,
            const unsigned short* __restrict__ Bg,
            float* __restrict__ C, int ldc, int K) {
    constexpr int BUFE = 32768;            // elements per K-tile buffer (A+B)
    __shared__ __align__(16) unsigned short lds[2 * BUFE];   // 128 KiB

    const int tid  = threadIdx.x;
    const int lane = tid & 63;
    const int wave = tid >> 6;
    const int mr   = lane & 15, q = lane >> 4;
    const int wr   = wave >> 2, wc = wave & 3;     // 2 x 4 wave grid
    const int wrb  = wr * 128, wcb = wc * 64;      // wave tile 128x64

    // bijective XCD-chunked swizzle over all 256 WGs
    const int gx = gridDim.x, gy = gridDim.y;
    const int flat = blockIdx.x + gx * (blockIdx.y + gy * blockIdx.z);
    const int nwg  = gx * gy * gridDim.z;          // 256
    const int swz  = (flat & 7) * (nwg >> 3) + (flat >> 3);
    const int mt = swz % gx;
    const int r1 = swz / gx;
    const int nt = r1 % gy;
    const int z  = r1 / gy;
    const int m0 = mt * 256, n0 = nt * 256;
    const int KH = K >> 1;                         // split-K half
    const int NT = KH >> 6;                        // K-tiles (BK=64)
    const size_t kb0 = (size_t)z * KH * 2;         // byte offset of K-half

    // staging geometry: half-tile = 128 rows x 64 k; 2 issues of
    // 512 thr x 16B. LDS dest linear (tid*16B); global src pre-swizzled.
    const int srow = tid >> 3;
    const int u16  = ((tid & 7) ^ (srow & 7)) * 16;
    const char* aGp = (const char*)Ag + (size_t)(m0 + srow) * (LDK * 2) + kb0 + u16;
    const char* bGp = (const char*)Bg + (size_t)(n0 + srow) * (LDK * 2) + kb0 + u16;

    auto stage_half = [&](int bufo, int X, int h, int ktile) {
        const char* g = X ? bGp : aGp;
#pragma unroll
        for (int j = 0; j < 2; ++j) {
            int rb = h * 128 + j * 64;
            gload16(g + (size_t)rb * (LDK * 2) + (size_t)ktile * 128,
                    lds + bufo + X * 16384 + rb * 64 + tid * 8);
        }
    };

    // fragment read slots (swizzle: slot = (kk*4+q) ^ (row&7); row&7 == mr&7)
    const int sK0 = ((q) ^ (mr & 7)) * 8;
    const int sK1 = ((4 + q) ^ (mr & 7)) * 8;

    f32x4 acc[8][4];
#pragma unroll
    for (int a = 0; a < 8; ++a)
#pragma unroll
        for (int b = 0; b < 4; ++b) acc[a][b] = (f32x4){0.f, 0.f, 0.f, 0.f};

    // prologue: buf0 <- kt0 (B0,B1,A0,A1), buf1 <- kt1 (B0,B1);
    // wait kt0 complete (vmcnt(4): kt1's 4 B-loads stay in flight)
    stage_half(0, 1, 0, 0);  stage_half(0, 1, 1, 0);
    stage_half(0, 0, 0, 0);  stage_half(0, 0, 1, 0);
    stage_half(BUFE, 1, 0, 1); stage_half(BUFE, 1, 1, 1);
    asm volatile("s_waitcnt vmcnt(4)" ::: "memory");
    __builtin_amdgcn_s_barrier();
    __builtin_amdgcn_sched_barrier(0);

    int cbo = 0, sbo = BUFE;
#pragma unroll 1
    for (int kt = 0; kt < NT; ++kt) {
        const bool st1 = (kt + 1 < NT), st2 = (kt + 2 < NT);
        const unsigned short* cb = lds + cbo;
        bf16x8 A03[4][2], A47[4][2], B01[2][2], B23[2][2];

        // ---------- P1: read A03 (8) + B01 (4); stage A-h0(kt+1); Q00 ----
#pragma unroll
        for (int mi = 0; mi < 4; ++mi) {
            const unsigned short* p = cb + (wrb + mi * 16 + mr) * 64;
            A03[mi][0] = *(const bf16x8*)(p + sK0);
            A03[mi][1] = *(const bf16x8*)(p + sK1);
        }
#pragma unroll
        for (int ni = 0; ni < 2; ++ni) {
            const unsigned short* p = cb + 16384 + (wcb + ni * 16 + mr) * 64;
            B01[ni][0] = *(const bf16x8*)(p + sK0);
            B01[ni][1] = *(const bf16x8*)(p + sK1);
        }
        if (st1) stage_half(sbo, 0, 0, kt + 1);
        __builtin_amdgcn_s_barrier();
        asm volatile("s_waitcnt lgkmcnt(0)" ::: "memory");
        __builtin_amdgcn_sched_barrier(0);
        __builtin_amdgcn_s_setprio(1);
#pragma unroll
        for (int mi = 0; mi < 4; ++mi)
#pragma unroll
            for (int ni = 0; ni < 2; ++ni)
#pragma unroll
                for (int kk = 0; kk < 2; ++kk)
                    acc[mi][ni] = __builtin_amdgcn_mfma_f32_16x16x32_bf16(
                        A03[mi][kk], B01[ni][kk], acc[mi][ni], 0, 0, 0);
        __builtin_amdgcn_s_setprio(0);
        __builtin_amdgcn_s_barrier();

        // ---------- P2: read B23 (4); stage A-h1(kt+1); Q01 --------------
#pragma unroll
        for (int ni = 0; ni < 2; ++ni) {
            const unsigned short* p = cb + 16384 + (wcb + (ni + 2) * 16 + mr) * 64;
            B23[ni][0] = *(const bf16x8*)(p + sK0);
            B23[ni][1] = *(const bf16x8*)(p + sK1);
        }
        if (st1) stage_half(sbo, 0, 1, kt + 1);
        __builtin_amdgcn_s_barrier();
        asm volatile("s_waitcnt lgkmcnt(0)" ::: "memory");
        __builtin_amdgcn_sched_barrier(0);
        __builtin_amdgcn_s_setprio(1);
#pragma unroll
        for (int mi = 0; mi < 4; ++mi)
#pragma unroll
            for (int ni = 0; ni < 2; ++ni)
#pragma unroll
                for (int kk = 0; kk < 2; ++kk)
                    acc[mi][ni + 2] = __builtin_amdgcn_mfma_f32_16x16x32_bf16(
                        A03[mi][kk], B23[ni][kk], acc[mi][ni + 2], 0, 0, 0);
        __builtin_amdgcn_s_setprio(0);
        __builtin_amdgcn_s_barrier();

        // ---------- P3: read A47 (8); stage B-h0(kt+2) into cb; Q11 ------
        // (cb's B region fully read as of P2-end barrier)
#pragma unroll
        for (int mi = 0; mi < 4; ++mi) {
            const unsigned short* p = cb + (wrb + (mi + 4) * 16 + mr) * 64;
            A47[mi][0] = *(const bf16x8*)(p + sK0);
            A47[mi][1] = *(const bf16x8*)(p + sK1);
        }
        if (st2) stage_half(cbo, 1, 0, kt + 2);
        __builtin_amdgcn_s_barrier();
        asm volatile("s_waitcnt lgkmcnt(0)" ::: "memory");
        __builtin_amdgcn_sched_barrier(0);
        __builtin_amdgcn_s_setprio(1);
#pragma unroll
        for (int mi = 0; mi < 4; ++mi)
#pragma unroll
            for (int ni = 0; ni < 2; ++ni)
#pragma unroll
                for (int kk = 0; kk < 2; ++kk)
                    acc[mi + 4][ni + 2] = __builtin_amdgcn_mfma_f32_16x16x32_bf16(
                        A47[mi][kk], B23[ni][kk], acc[mi + 4][ni + 2], 0, 0, 0);
        __builtin_amdgcn_s_setprio(0);
        __builtin_amdgcn_s_barrier();

        // ---------- P4: stage B-h1(kt+2) into cb; Q10; vmcnt(4) ----------
        if (st2) stage_half(cbo, 1, 1, kt + 2);
        __builtin_amdgcn_s_barrier();
        asm volatile("s_waitcnt lgkmcnt(0)" ::: "memory");
        __builtin_amdgcn_sched_barrier(0);
        __builtin_amdgcn_s_setprio(1);
#pragma unroll
        for (int mi = 0; mi < 4; ++mi)
#pragma unroll
            for (int ni = 0; ni < 2; ++ni)
#pragma unroll
                for (int kk = 0; kk < 2; ++kk)
                    acc[mi + 4][ni] = __builtin_amdgcn_mfma_f32_16x16x32_bf16(
                        A47[mi][kk], B01[ni][kk], acc[mi + 4][ni], 0, 0, 0);
        __builtin_amdgcn_s_setprio(0);
        // counted end-of-tile wait: kt+1's data (A-h1 staged at P2, 3
        // stage-points old) complete; kt+2's 4 B-loads stay in flight.
        if (st2)      asm volatile("s_waitcnt vmcnt(4)" ::: "memory");
        else if (st1) asm volatile("s_waitcnt vmcnt(0)" ::: "memory");
        __builtin_amdgcn_s_barrier();
        __builtin_amdgcn_sched_barrier(0);
        int t = cbo; cbo = sbo; sbo = t;
    }

    // C/D layout: col = lane&15, row = (lane>>4)*4 + reg
#pragma unroll
    for (int mi = 0; mi < 8; ++mi)
#pragma unroll
        for (int ni = 0; ni < 4; ++ni)
#pragma unroll
            for (int r = 0; r < 4; ++r) {
                int m = m0 + wrb + mi * 16 + q * 4 + r;
                int n = n0 + wcb + ni * 16 + mr;
                atomicAdd(&C[(size_t)m * ldc + n], acc[mi][ni][r]);
            }
}

// ---------------- zero fp32 buffer (for atomic accumulation) ------------
__global__ __launch_bounds__(256)
void zerof(float4* __restrict__ p) {
    int idx = blockIdx.x * 256 + threadIdx.x;
    p[idx] = (float4){0.f, 0.f, 0.f, 0.f};
}

// ---------------- MT fp32 -> bf16 ----------------
__global__ __launch_bounds__(256)
void cvt(const float* __restrict__ src, unsigned short* __restrict__ dst) {
    int idx = blockIdx.x * 256 + threadIdx.x;
    float4 v = ((const float4*)src)[idx];
    ushort4 o;
    o.x = f2bf(v.x); o.y = f2bf(v.y); o.z = f2bf(v.z); o.w = f2bf(v.w);
    ((ushort4*)dst)[idx] = o;
}

// ---------------- epilogue: re/im, row norm, scale (in place on d_out) ----
__global__ __launch_bounds__(256)
void epi(float* __restrict__ out, const float* __restrict__ pts,
         const float* __restrict__ A) {
    int n = blockIdx.x;
    int t = threadIdx.x;
    float x0 = pts[n * 3 + 0], x1 = pts[n * 3 + 1], x2 = pts[n * 3 + 2];
    float* row = out + (size_t)n * JD;
    float reA[2], imA[2];
    float ssum = 0.f;
#pragma unroll
    for (int u = 0; u < 2; ++u) {
        int j = t + u * 256;
        float pa = (x0 * A[j] + x1 * A[ENC + j] + x2 * A[2 * ENC + j]) * INV_R;
        float s, c;
        sincos_rev(pa, &s, &c);
        float gc = row[j], gs = row[ENC + j];
        float re = gc * c + gs * s;
        float im = gs * c - gc * s;
        reA[u] = re; imA[u] = im;
        ssum += re * re + im * im;
    }
#pragma unroll
    for (int off = 32; off > 0; off >>= 1) ssum += __shfl_down(ssum, off);
    __shared__ float red[4];
    if ((t & 63) == 0) red[t >> 6] = ssum;
    __syncthreads();
    float tot = red[0] + red[1] + red[2] + red[3];
    float scale = SQRT_D / sqrtf(tot);
#pragma unroll
    for (int u = 0; u < 2; ++u) {
        int j = t + u * 256;
        row[j]       = reA[u] * scale;
        row[ENC + j] = imA[u] * scale;
    }
}

extern "C" void kernel_launch(void* const* d_in, const int* in_sizes, int n_in,
                              void* d_out, int out_size, void* d_ws, size_t ws_size,
                              hipStream_t stream) {
    const float* pts = (const float*)d_in[0];
    const float* A   = (const float*)d_in[1];
    const float* B   = (const float*)d_in[2];
    float* out = (float*)d_out;
    char* ws = (char*)d_ws;

    // ws layout (~199 MiB):
    //   [0, 16M)          eAT  [1024][8192] bf16   (phase A)  / eB [8192][8192] (phase C, spans both)
    //   [16M, 151M)       eBT  [8192][8192] bf16   (phase A)
    //   [151M, 183M)      MTf  [1024][8192] fp32
    //   [183M, 199M)      MTb  [1024][8192] bf16
    unsigned short* eAT = (unsigned short*)ws;
    unsigned short* eBT = (unsigned short*)(ws + (size_t)JD * CH * 2);
    unsigned short* eBw = (unsigned short*)ws;
    size_t offMT = (size_t)(JD + ID) * CH * 2;
    float* MTf = (float*)(ws + offMT);
    unsigned short* MTb = (unsigned short*)(ws + offMT + (size_t)JD * ID * 4);

    // MT[j][i] = sum over all chunks: eAT[j][:] . eBT[i][:]
    zerof<<<dim3(8192), 256, 0, stream>>>((float4*)MTf);
    for (int c = 0; c < NCH; ++c) {
        gen_t<<<dim3(73728), 256, 0, stream>>>(pts, A, B, eAT, eBT, c * CH);
        // M=1024 (4 tiles), N=8192 (32 tiles), split-K=2 -> 256 WGs
        gemm8p<<<dim3(4, 32, 2), 512, 0, stream>>>(eAT, eBT, MTf, ID, CH);
    }
    cvt<<<dim3(8192), 256, 0, stream>>>(MTf, MTb);
    for (int c = 0; c < NCH; ++c) {
        gen_b<<<dim3(65536), 256, 0, stream>>>(pts, B, eBw, c * CH);
        // G[ln][j] = eB[ln][:] . MTb[j][:]  (M=8192: 32 tiles, N=1024: 4, z=2)
        zerof<<<dim3(8192), 256, 0, stream>>>(
            (float4*)(out + (size_t)c * CH * JD));
        gemm8p<<<dim3(32, 4, 2), 512, 0, stream>>>(
            eBw, MTb, out + (size_t)c * CH * JD, JD, ID);
    }
    epi<<<dim3(NPTS), 256, 0, stream>>>(out, pts, A);
}